// Round 9
// baseline (9294.121 us; speedup 1.0000x reference)
//
#include <hip/hip_runtime.h>
#include <hip/hip_fp16.h>

#define TT 256
#define NSL 8           // slices (blocks) per batch element
#define KR 64           // enc k-rows per slice
#define NPAD 10112
#define LIM (1 << 17)

typedef _Float16 f16;
typedef _Float16 f16x8 __attribute__((ext_vector_type(8)));
typedef float f32x2 __attribute__((ext_vector_type(2)));
typedef float f32x4 __attribute__((ext_vector_type(4)));

// ---- per-b exchange layout (floats, per parity region). All entries are
// (value, tag) 8B pairs; PP/CP are [tid][slice] so readers gather 64B runs.
#define H0_OFF 0        // 256 pairs = 512
#define PP_OFF 512      // 512 x 8 pairs = 8192
#define MS_OFF 8704     // 8 x (m,S,tag,tag) quads = 32
#define CP_OFF 8736     // 512 x 8 pairs = 8192
#define PAR_STRIDE 16960
#define XC_STRIDE 34048ull

// ---- ws layout (bytes) ----
#define GE_OFF 4096ull
#define GE_BYTES (8192ull*1024ull*4ull)
#define XC_OFF (GE_OFF + GE_BYTES)
#define XC_BYTES (32ull*XC_STRIDE*4ull)
#define PC_OFF (XC_OFF + XC_BYTES)
#define PC_BYTES (8192ull*1024ull*2ull)
#define WO_OFF (PC_OFF + PC_BYTES)

__device__ __forceinline__ float sigm(float x) { return 1.f / (1.f + __expf(-x)); }

// ---- fire-and-forget MALL stores (self-tagged payloads, no acks) ----
__device__ __forceinline__ void st2f(float* p, float v, float tagf) {
  f32x2 x; x[0] = v; x[1] = tagf;
  asm volatile("global_store_dwordx2 %0, %1, off sc0 sc1" :: "v"(p), "v"(x) : "memory");
}
__device__ __forceinline__ void st4f(float* p, f32x4 v) {
  asm volatile("global_store_dwordx4 %0, %1, off sc0 sc1" :: "v"(p), "v"(v) : "memory");
}
// ---- gathers (with waitcnt) ----
__device__ __forceinline__ f32x2 ld2(const float* p) {
  f32x2 r;
  asm volatile("global_load_dwordx2 %0, %1, off sc0 sc1\n\ts_waitcnt vmcnt(0)"
               : "=v"(r) : "v"(p) : "memory");
  return r;
}
// 4 dwordx4 from one base (64B run), one waitcnt
__device__ __forceinline__ void ld4q(const float* p, f32x4* o) {
  asm volatile(
    "global_load_dwordx4 %0, %4, off sc0 sc1\n\t"
    "global_load_dwordx4 %1, %4, off offset:16 sc0 sc1\n\t"
    "global_load_dwordx4 %2, %4, off offset:32 sc0 sc1\n\t"
    "global_load_dwordx4 %3, %4, off offset:48 sc0 sc1\n\t"
    "s_waitcnt vmcnt(0)"
    : "=&v"(o[0]), "=&v"(o[1]), "=&v"(o[2]), "=&v"(o[3])
    : "v"(p) : "memory");
}
// 4 dwordx4 + 1 MS quad, one waitcnt
__device__ __forceinline__ void ld4q_ms(const float* p, const float* msp,
                                        f32x4* o, f32x4* ms) {
  asm volatile(
    "global_load_dwordx4 %0, %5, off sc0 sc1\n\t"
    "global_load_dwordx4 %1, %5, off offset:16 sc0 sc1\n\t"
    "global_load_dwordx4 %2, %5, off offset:32 sc0 sc1\n\t"
    "global_load_dwordx4 %3, %5, off offset:48 sc0 sc1\n\t"
    "global_load_dwordx4 %4, %6, off sc0 sc1\n\t"
    "s_waitcnt vmcnt(0)"
    : "=&v"(o[0]), "=&v"(o[1]), "=&v"(o[2]), "=&v"(o[3]), "=&v"(*ms)
    : "v"(p), "v"(msp) : "memory");
}

__device__ __forceinline__ float dot8(f16x8 w, const float* x) {
  return (float)w[0]*x[0] + (float)w[1]*x[1] + (float)w[2]*x[2] + (float)w[3]*x[3]
       + (float)w[4]*x[4] + (float)w[5]*x[5] + (float)w[6]*x[6] + (float)w[7]*x[7];
}

// ---- K1: tokens -> embedding -> g_e = e @ W_e^T + b0 ----
__global__ __launch_bounds__(256) void k_embed_gates(
    const int* __restrict__ dec, const float* __restrict__ emb,
    const float* __restrict__ Wih0, const float* __restrict__ b0,
    float* __restrict__ ge)
{
  __shared__ float e_lds[8][64];
  int tid = threadIdx.x;
  int tb0 = blockIdx.x * 8;
  for (int j = tid; j < 8 * 64; j += 256) {
    int q = j >> 6, d = j & 63;
    int tb = tb0 + q;
    int t = tb >> 5, b = tb & 31;
    int tok;
    if (t == 0) tok = 1;
    else { tok = dec[b * 256 + (t - 1)]; if (tok == 2) tok = 0; }
    e_lds[q][d] = emb[(size_t)tok * 64 + d];
  }
  __syncthreads();
  for (int rr = 0; rr < 4; ++rr) {
    int row = tid + rr * 256;
    float bv = b0[row];
    float acc[8];
#pragma unroll
    for (int q = 0; q < 8; ++q) acc[q] = bv;
    const float* wr = Wih0 + (size_t)row * 576;
#pragma unroll 4
    for (int d4 = 0; d4 < 16; ++d4) {
      float4 w = *(const float4*)&wr[d4 * 4];
#pragma unroll
      for (int q = 0; q < 8; ++q) {
        acc[q] += w.x * e_lds[q][d4 * 4 + 0];
        acc[q] += w.y * e_lds[q][d4 * 4 + 1];
        acc[q] += w.z * e_lds[q][d4 * 4 + 2];
        acc[q] += w.w * e_lds[q][d4 * 4 + 3];
      }
    }
#pragma unroll
    for (int q = 0; q < 8; ++q) ge[(size_t)(tb0 + q) * 1024 + row] = acc[q];
  }
}

// ---- K1b: W_out fp32 -> fp16, padded ----
__global__ __launch_bounds__(256) void k_wout_f16(const float* __restrict__ W, f16* __restrict__ wo)
{
  size_t base = (size_t)blockIdx.x * 4096 + (size_t)threadIdx.x * 16;
  for (int i = 0; i < 16; ++i) {
    size_t idx = base + i;
    size_t n = idx >> 10;
    float v = (n < 10000) ? W[idx] : 0.f;
    wo[idx] = (f16)v;
  }
}

// ---- K2: 8 slices x 512 threads per b; tag-in-data poll-gather exchanges ----
__global__ __launch_bounds__(512, 2) void k_seq(
    const float* __restrict__ enc, const float* __restrict__ Wih0,
    const float* __restrict__ Wih1, const float* __restrict__ b1,
    const float* __restrict__ Wproj, const float* __restrict__ bproj,
    const float* __restrict__ ge, float* __restrict__ xc,
    f16* __restrict__ pc)
{
  __shared__ f16 ench[KR * 512];       // 64KB
  __shared__ float ctx_lds[512];
  __shared__ float hbuf[256];
  __shared__ float projf[512];
  __shared__ float gred[96];
  __shared__ float h1buf[32];
  __shared__ float sc_lds[64];
  __shared__ float el[64];
  __shared__ int dead;

  int tid = threadIdx.x;
  int j = blockIdx.x;
  int b = j & 31;                 // slices of b share blockIdx%8 residue
  int s = j >> 5;
  float* xcb = xc + (size_t)b * XC_STRIDE;

  int rr = tid >> 2, c4 = tid & 3;
  int rp = tid >> 3, c8 = tid & 7;

  // ---- fp16 register-stationary weights ----
  f16x8 wA[16];   // Wih0 ctx part: own gate row, 128 cols
  f16x8 wB[8];    // Wih1: own gate row, 64 cols
  f16x8 wp[4];    // Wproj: own row, 32 cols
  int rowA = 0; float b1v = 0.f;
  if (rr < 96) {
    int g = rr >> 5, d = rr & 31;
    rowA = (g == 0 ? 0 : g == 1 ? 512 : 768) + s * 32 + d;
    const float* wra = Wih0 + (size_t)rowA * 576 + 64 + c4 * 128;
#pragma unroll
    for (int i = 0; i < 16; ++i) {
      float4 x0 = ((const float4*)wra)[2 * i];
      float4 x1 = ((const float4*)wra)[2 * i + 1];
      f16x8 w;
      w[0]=(f16)x0.x; w[1]=(f16)x0.y; w[2]=(f16)x0.z; w[3]=(f16)x0.w;
      w[4]=(f16)x1.x; w[5]=(f16)x1.y; w[6]=(f16)x1.z; w[7]=(f16)x1.w;
      wA[i] = w;
    }
    const float* wrb = Wih1 + (size_t)rowA * 256 + c4 * 64;
#pragma unroll
    for (int i = 0; i < 8; ++i) {
      float4 x0 = ((const float4*)wrb)[2 * i];
      float4 x1 = ((const float4*)wrb)[2 * i + 1];
      f16x8 w;
      w[0]=(f16)x0.x; w[1]=(f16)x0.y; w[2]=(f16)x0.z; w[3]=(f16)x0.w;
      w[4]=(f16)x1.x; w[5]=(f16)x1.y; w[6]=(f16)x1.z; w[7]=(f16)x1.w;
      wB[i] = w;
    }
    b1v = b1[rowA];
  }
  {
    const float* wpr = Wproj + (size_t)tid * 256 + s * 32;
#pragma unroll
    for (int i = 0; i < 4; ++i) {
      float4 x0 = ((const float4*)wpr)[2 * i];
      float4 x1 = ((const float4*)wpr)[2 * i + 1];
      f16x8 w;
      w[0]=(f16)x0.x; w[1]=(f16)x0.y; w[2]=(f16)x0.z; w[3]=(f16)x0.w;
      w[4]=(f16)x1.x; w[5]=(f16)x1.y; w[6]=(f16)x1.z; w[7]=(f16)x1.w;
      wp[i] = w;
    }
  }
  float bpv = bproj[tid];

  // stationary enc slice -> LDS fp16, xor swizzle on d by (kk&7)<<3
  for (int i = tid; i < KR * 512; i += 512) {
    int kk = i >> 9, d = i & 511;
    float v = enc[((size_t)b * 512 + s * KR + kk) * 512 + d];
    ench[kk * 512 + (d ^ ((kk & 7) << 3))] = (f16)v;
  }
  ctx_lds[tid] = 0.f;
  if (tid == 0) dead = 0;
  __syncthreads();

  float gev = 0.f;
  if (rr < 96 && c4 == 0) gev = ge[(size_t)b * 1024 + rowA];   // t=0

  for (int t = 0; t < TT; ++t) {
    float* P = xcb + (t & 1) * PAR_STRIDE;
    int tag = t + 1;
    float tagf = __int_as_float(tag);

    // ---- stage A: own L0 gate rows = g_e + W_c @ ctx -> post own h0[32] ----
    if (rr < 96) {
      float acc = 0.f;
#pragma unroll
      for (int i = 0; i < 16; ++i)
        acc += dot8(wA[i], &ctx_lds[c4 * 128 + i * 8]);
      acc += __shfl_xor(acc, 1, 64);
      acc += __shfl_xor(acc, 2, 64);
      if (c4 == 0) gred[rr] = acc + gev;
    }
    __syncthreads();
    if (tid < 32) {
      float cc = sigm(gred[tid]) * tanhf(gred[32 + tid]);
      float h = sigm(gred[64 + tid]) * tanhf(cc);
      st2f(P + H0_OFF + 2 * (s * 32 + tid), h, tagf);   // fire-and-forget
    }

    // prefetch next ge (overlaps exchange)
    if (t + 1 < TT && rr < 96 && c4 == 0)
      gev = ge[(size_t)((t + 1) * 32 + b) * 1024 + rowA];

    // ---- exchange 1: poll-gather h0 (tid<256 read one pair each) ----
    {
      int it = 0;
      for (;;) {
        int myok = 1;
        if (tid < 256) {
          f32x2 hv = ld2(P + H0_OFF + 2 * tid);
          myok = (__float_as_int(hv[1]) == tag);
          if (myok) hbuf[tid] = hv[0];
        }
        if (++it > LIM) { dead = 1; myok = 1; }
        if (__syncthreads_and(myok)) break;
        __builtin_amdgcn_s_sleep(1);
      }
    }
    if (dead) break;

    // ---- stage B: own L1 gate rows -> own h1[32] ----
    if (rr < 96) {
      float acc = 0.f;
#pragma unroll
      for (int i = 0; i < 8; ++i)
        acc += dot8(wB[i], &hbuf[c4 * 64 + i * 8]);
      acc += __shfl_xor(acc, 1, 64);
      acc += __shfl_xor(acc, 2, 64);
      if (c4 == 0) gred[rr] = acc + b1v;
    }
    __syncthreads();
    if (tid < 32) {
      float cc = sigm(gred[tid]) * tanhf(gred[32 + tid]);
      h1buf[tid] = sigm(gred[64 + tid]) * tanhf(cc);
    }
    __syncthreads();

    // ---- stage B2: proj partial post (pair per thread) ----
    {
      float acc = 0.f;
#pragma unroll
      for (int i = 0; i < 4; ++i)
        acc += dot8(wp[i], &h1buf[i * 8]);
      st2f(P + PP_OFF + (tid * 8 + s) * 2, acc, tagf);
    }

    // ---- exchange 2: poll-gather 8 proj partials (64B run per thread) ----
    {
      int it = 0;
      for (;;) {
        f32x4 o[4];
        ld4q(P + PP_OFF + 16 * tid, o);
        int myok = (__float_as_int(o[0][1]) == tag) & (__float_as_int(o[0][3]) == tag)
                 & (__float_as_int(o[1][1]) == tag) & (__float_as_int(o[1][3]) == tag)
                 & (__float_as_int(o[2][1]) == tag) & (__float_as_int(o[2][3]) == tag)
                 & (__float_as_int(o[3][1]) == tag) & (__float_as_int(o[3][3]) == tag);
        if (++it > LIM) { dead = 1; myok = 1; }
        if (__syncthreads_and(myok)) {
          float v = bpv + o[0][0] + o[0][2] + o[1][0] + o[1][2]
                        + o[2][0] + o[2][2] + o[3][0] + o[3][2];
          v = fmaxf(v, 0.f);
          projf[tid] = v;
          if (s == 0) pc[(size_t)(b * 256 + t) * 1024 + tid] = (f16)v;
          break;
        }
        __builtin_amdgcn_s_sleep(1);
      }
    }
    __syncthreads();
    if (dead) break;

    // ---- stage D: scores (own 64 k-rows), local softmax, ctx partial post ----
    {
      int kk = rp;                       // 0..63
      int swz = (kk & 7) << 3;
      float acc = 0.f;
#pragma unroll
      for (int j0 = 0; j0 < 8; ++j0) {
        int d = j0 * 64 + c8 * 8;
        f16x8 v = *(const f16x8*)&ench[kk * 512 + (d ^ swz)];
        float4 p0 = *(const float4*)&projf[d];
        float4 p1 = *(const float4*)&projf[d + 4];
        acc += (float)v[0]*p0.x + (float)v[1]*p0.y + (float)v[2]*p0.z + (float)v[3]*p0.w;
        acc += (float)v[4]*p1.x + (float)v[5]*p1.y + (float)v[6]*p1.z + (float)v[7]*p1.w;
      }
      acc += __shfl_xor(acc, 1, 64);
      acc += __shfl_xor(acc, 2, 64);
      acc += __shfl_xor(acc, 4, 64);
      if (c8 == 0) sc_lds[kk] = acc;
    }
    __syncthreads();
    if (tid < 64) {
      float v = sc_lds[tid];
      float m = v;
      m = fmaxf(m, __shfl_xor(m, 32, 64));
      m = fmaxf(m, __shfl_xor(m, 16, 64));
      m = fmaxf(m, __shfl_xor(m, 8, 64));
      m = fmaxf(m, __shfl_xor(m, 4, 64));
      m = fmaxf(m, __shfl_xor(m, 2, 64));
      m = fmaxf(m, __shfl_xor(m, 1, 64));
      float e = __expf(v - m);
      el[tid] = e;
      float S = e;
      S += __shfl_xor(S, 32, 64);
      S += __shfl_xor(S, 16, 64);
      S += __shfl_xor(S, 8, 64);
      S += __shfl_xor(S, 4, 64);
      S += __shfl_xor(S, 2, 64);
      S += __shfl_xor(S, 1, 64);
      if (tid == 0) {
        f32x4 q; q[0] = m; q[1] = S; q[2] = tagf; q[3] = tagf;
        st4f(P + MS_OFF + 4 * s, q);
      }
    }
    __syncthreads();
    {
      float c = 0.f;
#pragma unroll 8
      for (int kk = 0; kk < 64; ++kk)
        c += el[kk] * (float)ench[kk * 512 + (tid ^ ((kk & 7) << 3))];
      st2f(P + CP_OFF + (tid * 8 + s) * 2, c, tagf);
    }

    // ---- exchange 3: poll-gather 8 ctx partials + (m,S) of slice (tid&7) ----
    {
      int it = 0;
      for (;;) {
        f32x4 o[4], ms;
        ld4q_ms(P + CP_OFF + 16 * tid, P + MS_OFF + 4 * (tid & 7), o, &ms);
        int myok = (__float_as_int(o[0][1]) == tag) & (__float_as_int(o[0][3]) == tag)
                 & (__float_as_int(o[1][1]) == tag) & (__float_as_int(o[1][3]) == tag)
                 & (__float_as_int(o[2][1]) == tag) & (__float_as_int(o[2][3]) == tag)
                 & (__float_as_int(o[3][1]) == tag) & (__float_as_int(o[3][3]) == tag)
                 & (__float_as_int(ms[2]) == tag);
        if (++it > LIM) { dead = 1; myok = 1; }
        if (__syncthreads_and(myok)) {
          float m = ms[0], S = ms[1];
          float mg = m;
          mg = fmaxf(mg, __shfl_xor(mg, 1, 8));
          mg = fmaxf(mg, __shfl_xor(mg, 2, 8));
          mg = fmaxf(mg, __shfl_xor(mg, 4, 8));
          float w = __expf(m - mg);
          float Sg = w * S;
          Sg += __shfl_xor(Sg, 1, 8);
          Sg += __shfl_xor(Sg, 2, 8);
          Sg += __shfl_xor(Sg, 4, 8);
          float inv = 1.f / Sg;
          float v = __shfl(w, 0, 8) * o[0][0] + __shfl(w, 1, 8) * o[0][2]
                  + __shfl(w, 2, 8) * o[1][0] + __shfl(w, 3, 8) * o[1][2]
                  + __shfl(w, 4, 8) * o[2][0] + __shfl(w, 5, 8) * o[2][2]
                  + __shfl(w, 6, 8) * o[3][0] + __shfl(w, 7, 8) * o[3][2];
          v *= inv;
          ctx_lds[tid] = v;
          if (s == 0) pc[(size_t)(b * 256 + t) * 1024 + 512 + tid] = (f16)v;
          break;
        }
        __builtin_amdgcn_s_sleep(1);
      }
    }
    __syncthreads();
    if (dead) break;
  }
}

// ---- K3: OUT[8192,10000] = PC[8192,1024] @ Wout16^T, fp16 MFMA ----
__global__ __launch_bounds__(256) void k_gemm(
    const f16* __restrict__ A, const f16* __restrict__ Bm, float* __restrict__ C)
{
  __shared__ f16 Ah[128 * 40];
  __shared__ f16 Bh[128 * 40];
  int tid = threadIdx.x;
  int tn = blockIdx.x;
  int tm = blockIdx.y;
  int lane = tid & 63, wave = tid >> 6;
  int wm = wave >> 1, wn = wave & 1;
  f32x4 acc[4][4];
#pragma unroll
  for (int i = 0; i < 4; ++i)
#pragma unroll
    for (int q = 0; q < 4; ++q) acc[i][q] = (f32x4){0.f, 0.f, 0.f, 0.f};

  for (int k0 = 0; k0 < 1024; k0 += 32) {
#pragma unroll
    for (int rd = 0; rd < 2; ++rd) {
      int chunk = tid + rd * 256;
      int row = chunk >> 2, cc = (chunk & 3) * 8;
      *(f16x8*)&Ah[row * 40 + cc] = *(const f16x8*)&A[((size_t)(tm * 128 + row)) * 1024 + k0 + cc];
      *(f16x8*)&Bh[row * 40 + cc] = *(const f16x8*)&Bm[((size_t)(tn * 128 + row)) * 1024 + k0 + cc];
    }
    __syncthreads();
    f16x8 af[4], bf[4];
#pragma unroll
    for (int q = 0; q < 4; ++q) {
      af[q] = *(const f16x8*)&Ah[(wm * 64 + q * 16 + (lane & 15)) * 40 + (lane >> 4) * 8];
      bf[q] = *(const f16x8*)&Bh[(wn * 64 + q * 16 + (lane & 15)) * 40 + (lane >> 4) * 8];
    }
#pragma unroll
    for (int i = 0; i < 4; ++i)
#pragma unroll
      for (int q = 0; q < 4; ++q)
        acc[i][q] = __builtin_amdgcn_mfma_f32_16x16x32_f16(af[i], bf[q], acc[i][q], 0, 0, 0);
    __syncthreads();
  }

  int rbase = (lane >> 4) * 4;
  int nloc = lane & 15;
#pragma unroll
  for (int i = 0; i < 4; ++i)
#pragma unroll
    for (int q = 0; q < 4; ++q)
#pragma unroll
      for (int rr = 0; rr < 4; ++rr) {
        int m = tm * 128 + wm * 64 + i * 16 + rbase + rr;
        int n = tn * 128 + wn * 64 + q * 16 + nloc;
        if (n < 10000) C[(size_t)m * 10000 + n] = acc[i][q][rr];
      }
}

extern "C" void kernel_launch(void* const* d_in, const int* in_sizes, int n_in,
                              void* d_out, int out_size, void* d_ws, size_t ws_size,
                              hipStream_t stream)
{
  const float* enc   = (const float*)d_in[0];
  const int*   dec   = (const int*)d_in[1];
  const float* emb   = (const float*)d_in[2];
  const float* Wih0  = (const float*)d_in[3];
  const float* b0    = (const float*)d_in[4];
  const float* Wih1  = (const float*)d_in[5];
  const float* b1    = (const float*)d_in[6];
  const float* Wproj = (const float*)d_in[7];
  const float* bproj = (const float*)d_in[8];
  const float* Wout  = (const float*)d_in[9];
  float* out = (float*)d_out;
  char* ws = (char*)d_ws;

  // zero the exchange region (tags must start at 0)
  hipMemsetAsync(ws + XC_OFF, 0, XC_BYTES, stream);
  k_embed_gates<<<1024, 256, 0, stream>>>(dec, emb, Wih0, b0, (float*)(ws + GE_OFF));
  k_wout_f16<<<(NPAD * 1024) / 4096, 256, 0, stream>>>(Wout, (f16*)(ws + WO_OFF));
  k_seq<<<256, 512, 0, stream>>>(enc, Wih0, Wih1, b1, Wproj, bproj,
                                 (float*)(ws + GE_OFF), (float*)(ws + XC_OFF),
                                 (f16*)(ws + PC_OFF));
  dim3 g3(79, 64);
  k_gemm<<<g3, 256, 0, stream>>>((const f16*)(ws + PC_OFF), (const f16*)(ws + WO_OFF), out);
}

// Round 10
// 7516.255 us; speedup vs baseline: 1.2365x; 1.2365x over previous
//
#include <hip/hip_runtime.h>
#include <hip/hip_fp16.h>

#define TT 256
#define NSL 8           // slices (blocks) per batch element
#define KR 64           // enc k-rows per slice
#define NPAD 10112
#define LIM (1 << 17)

typedef _Float16 f16;
typedef _Float16 f16x2h __attribute__((ext_vector_type(2)));
typedef _Float16 f16x8 __attribute__((ext_vector_type(8)));
typedef float f32x2 __attribute__((ext_vector_type(2)));
typedef float f32x4 __attribute__((ext_vector_type(4)));

// ---- per-b exchange layout (floats, per parity region). All entries are
// (value, tag) 8B pairs stored atomically; PP/CP are [tid][slice] so each
// reader's 8 partials are one 64B run.
#define H0_OFF 0        // 256 pairs = 512
#define PP_OFF 512      // 512 x 8 pairs = 8192
#define MS_OFF 8704     // 8 x (m,S,tag,tag) quads = 32
#define CP_OFF 8736     // 512 x 8 pairs = 8192
#define PAR_STRIDE 16960
#define XC_STRIDE 34048ull

// ---- ws layout (bytes) ----
#define GE_OFF 4096ull
#define GE_BYTES (8192ull*1024ull*4ull)
#define XC_OFF (GE_OFF + GE_BYTES)
#define XC_BYTES (32ull*XC_STRIDE*4ull)
#define PC_OFF (XC_OFF + XC_BYTES)
#define PC_BYTES (8192ull*1024ull*2ull)
#define WO_OFF (PC_OFF + PC_BYTES)

__device__ __forceinline__ float sigm(float x) { return 1.f / (1.f + __expf(-x)); }

// ---- fire-and-forget MALL stores (self-tagged payloads, no acks) ----
__device__ __forceinline__ void st2f(float* p, float v, float tagf) {
  f32x2 x; x[0] = v; x[1] = tagf;
  asm volatile("global_store_dwordx2 %0, %1, off sc0 sc1" :: "v"(p), "v"(x) : "memory");
}
__device__ __forceinline__ void st4f(float* p, f32x4 v) {
  asm volatile("global_store_dwordx4 %0, %1, off sc0 sc1" :: "v"(p), "v"(v) : "memory");
}
// ---- gathers (with waitcnt) ----
__device__ __forceinline__ f32x2 ld2(const float* p) {
  f32x2 r;
  asm volatile("global_load_dwordx2 %0, %1, off sc0 sc1\n\ts_waitcnt vmcnt(0)"
               : "=v"(r) : "v"(p) : "memory");
  return r;
}
// 4 dwordx4 from one base (64B run), one waitcnt
__device__ __forceinline__ void ld4q(const float* p, f32x4* o) {
  asm volatile(
    "global_load_dwordx4 %0, %4, off sc0 sc1\n\t"
    "global_load_dwordx4 %1, %4, off offset:16 sc0 sc1\n\t"
    "global_load_dwordx4 %2, %4, off offset:32 sc0 sc1\n\t"
    "global_load_dwordx4 %3, %4, off offset:48 sc0 sc1\n\t"
    "s_waitcnt vmcnt(0)"
    : "=&v"(o[0]), "=&v"(o[1]), "=&v"(o[2]), "=&v"(o[3])
    : "v"(p) : "memory");
}
// 4 dwordx4 + 1 MS quad, one waitcnt
__device__ __forceinline__ void ld4q_ms(const float* p, const float* msp,
                                        f32x4* o, f32x4* ms) {
  asm volatile(
    "global_load_dwordx4 %0, %5, off sc0 sc1\n\t"
    "global_load_dwordx4 %1, %5, off offset:16 sc0 sc1\n\t"
    "global_load_dwordx4 %2, %5, off offset:32 sc0 sc1\n\t"
    "global_load_dwordx4 %3, %5, off offset:48 sc0 sc1\n\t"
    "global_load_dwordx4 %4, %6, off sc0 sc1\n\t"
    "s_waitcnt vmcnt(0)"
    : "=&v"(o[0]), "=&v"(o[1]), "=&v"(o[2]), "=&v"(o[3]), "=&v"(*ms)
    : "v"(p), "v"(msp) : "memory");
}

// ---- f16 dot: 8 MACs via 4x v_dot2_f32_f16 ----
#if defined(__has_builtin)
#if __has_builtin(__builtin_amdgcn_fdot2)
#define HAS_FDOT2 1
#endif
#endif
__device__ __forceinline__ float dot8h(f16x8 w, const f16* x, float acc) {
#ifdef HAS_FDOT2
  const f16x2h* xp = (const f16x2h*)x;
  f16x2h w0; w0[0] = w[0]; w0[1] = w[1];
  f16x2h w1; w1[0] = w[2]; w1[1] = w[3];
  f16x2h w2; w2[0] = w[4]; w2[1] = w[5];
  f16x2h w3; w3[0] = w[6]; w3[1] = w[7];
  acc = __builtin_amdgcn_fdot2(w0, xp[0], acc, false);
  acc = __builtin_amdgcn_fdot2(w1, xp[1], acc, false);
  acc = __builtin_amdgcn_fdot2(w2, xp[2], acc, false);
  acc = __builtin_amdgcn_fdot2(w3, xp[3], acc, false);
#else
#pragma unroll
  for (int i = 0; i < 8; ++i) acc += (float)w[i] * (float)x[i];
#endif
  return acc;
}

// ---- K1: tokens -> embedding -> g_e = e @ W_e^T + b0 ----
__global__ __launch_bounds__(256) void k_embed_gates(
    const int* __restrict__ dec, const float* __restrict__ emb,
    const float* __restrict__ Wih0, const float* __restrict__ b0,
    float* __restrict__ ge)
{
  __shared__ float e_lds[8][64];
  int tid = threadIdx.x;
  int tb0 = blockIdx.x * 8;
  for (int j = tid; j < 8 * 64; j += 256) {
    int q = j >> 6, d = j & 63;
    int tb = tb0 + q;
    int t = tb >> 5, b = tb & 31;
    int tok;
    if (t == 0) tok = 1;
    else { tok = dec[b * 256 + (t - 1)]; if (tok == 2) tok = 0; }
    e_lds[q][d] = emb[(size_t)tok * 64 + d];
  }
  __syncthreads();
  for (int rr = 0; rr < 4; ++rr) {
    int row = tid + rr * 256;
    float bv = b0[row];
    float acc[8];
#pragma unroll
    for (int q = 0; q < 8; ++q) acc[q] = bv;
    const float* wr = Wih0 + (size_t)row * 576;
#pragma unroll 4
    for (int d4 = 0; d4 < 16; ++d4) {
      float4 w = *(const float4*)&wr[d4 * 4];
#pragma unroll
      for (int q = 0; q < 8; ++q) {
        acc[q] += w.x * e_lds[q][d4 * 4 + 0];
        acc[q] += w.y * e_lds[q][d4 * 4 + 1];
        acc[q] += w.z * e_lds[q][d4 * 4 + 2];
        acc[q] += w.w * e_lds[q][d4 * 4 + 3];
      }
    }
#pragma unroll
    for (int q = 0; q < 8; ++q) ge[(size_t)(tb0 + q) * 1024 + row] = acc[q];
  }
}

// ---- K1b: W_out fp32 -> fp16, padded ----
__global__ __launch_bounds__(256) void k_wout_f16(const float* __restrict__ W, f16* __restrict__ wo)
{
  size_t base = (size_t)blockIdx.x * 4096 + (size_t)threadIdx.x * 16;
  for (int i = 0; i < 16; ++i) {
    size_t idx = base + i;
    size_t n = idx >> 10;
    float v = (n < 10000) ? W[idx] : 0.f;
    wo[idx] = (f16)v;
  }
}

// ---- K2: 8 slices x 512 threads per b; tag-in-data exchanges with
//      PER-LANE narrow retry loops (no barrier inside the poll). ----
__global__ __launch_bounds__(512, 2) void k_seq(
    const float* __restrict__ enc, const float* __restrict__ Wih0,
    const float* __restrict__ Wih1, const float* __restrict__ b1,
    const float* __restrict__ Wproj, const float* __restrict__ bproj,
    const float* __restrict__ ge, float* __restrict__ xc,
    f16* __restrict__ pc)
{
  __shared__ f16 ench[KR * 512];       // 64KB
  __shared__ f16 ctxh[512];
  __shared__ f16 hbufh[256];
  __shared__ f16 projh[512];
  __shared__ f16 h1h[32];
  __shared__ float gred[96];
  __shared__ float sc_lds[64];
  __shared__ float el[64];
  __shared__ int dead;

  int tid = threadIdx.x;
  int j = blockIdx.x;
  int b = j & 31;                 // slices of b share blockIdx%8 residue
  int s = j >> 5;
  float* xcb = xc + (size_t)b * XC_STRIDE;

  int rr = tid >> 2, c4 = tid & 3;
  int rp = tid >> 3, c8 = tid & 7;

  // ---- fp16 register-stationary weights ----
  f16x8 wA[16];   // Wih0 ctx part: own gate row, 128 cols
  f16x8 wB[8];    // Wih1: own gate row, 64 cols
  f16x8 wp[4];    // Wproj: own row, 32 cols
  int rowA = 0; float b1v = 0.f;
  if (rr < 96) {
    int g = rr >> 5, d = rr & 31;
    rowA = (g == 0 ? 0 : g == 1 ? 512 : 768) + s * 32 + d;
    const float* wra = Wih0 + (size_t)rowA * 576 + 64 + c4 * 128;
#pragma unroll
    for (int i = 0; i < 16; ++i) {
      float4 x0 = ((const float4*)wra)[2 * i];
      float4 x1 = ((const float4*)wra)[2 * i + 1];
      f16x8 w;
      w[0]=(f16)x0.x; w[1]=(f16)x0.y; w[2]=(f16)x0.z; w[3]=(f16)x0.w;
      w[4]=(f16)x1.x; w[5]=(f16)x1.y; w[6]=(f16)x1.z; w[7]=(f16)x1.w;
      wA[i] = w;
    }
    const float* wrb = Wih1 + (size_t)rowA * 256 + c4 * 64;
#pragma unroll
    for (int i = 0; i < 8; ++i) {
      float4 x0 = ((const float4*)wrb)[2 * i];
      float4 x1 = ((const float4*)wrb)[2 * i + 1];
      f16x8 w;
      w[0]=(f16)x0.x; w[1]=(f16)x0.y; w[2]=(f16)x0.z; w[3]=(f16)x0.w;
      w[4]=(f16)x1.x; w[5]=(f16)x1.y; w[6]=(f16)x1.z; w[7]=(f16)x1.w;
      wB[i] = w;
    }
    b1v = b1[rowA];
  }
  {
    const float* wpr = Wproj + (size_t)tid * 256 + s * 32;
#pragma unroll
    for (int i = 0; i < 4; ++i) {
      float4 x0 = ((const float4*)wpr)[2 * i];
      float4 x1 = ((const float4*)wpr)[2 * i + 1];
      f16x8 w;
      w[0]=(f16)x0.x; w[1]=(f16)x0.y; w[2]=(f16)x0.z; w[3]=(f16)x0.w;
      w[4]=(f16)x1.x; w[5]=(f16)x1.y; w[6]=(f16)x1.z; w[7]=(f16)x1.w;
      wp[i] = w;
    }
  }
  float bpv = bproj[tid];

  // stationary enc slice -> LDS fp16, xor swizzle on d by (kk&7)<<3
  for (int i = tid; i < KR * 512; i += 512) {
    int kk = i >> 9, d = i & 511;
    float v = enc[((size_t)b * 512 + s * KR + kk) * 512 + d];
    ench[kk * 512 + (d ^ ((kk & 7) << 3))] = (f16)v;
  }
  ctxh[tid] = (f16)0.f;
  if (tid == 0) dead = 0;
  __syncthreads();

  float gev = 0.f;
  if (rr < 96 && c4 == 0) gev = ge[(size_t)b * 1024 + rowA];   // t=0

  for (int t = 0; t < TT; ++t) {
    float* P = xcb + (t & 1) * PAR_STRIDE;
    int tag = t + 1;
    float tagf = __int_as_float(tag);

    // ---- stage A: own L0 gate rows = g_e + W_c @ ctx -> post own h0[32] ----
    if (rr < 96) {
      float acc = 0.f;
#pragma unroll
      for (int i = 0; i < 16; ++i)
        acc = dot8h(wA[i], &ctxh[c4 * 128 + i * 8], acc);
      acc += __shfl_xor(acc, 1, 64);
      acc += __shfl_xor(acc, 2, 64);
      if (c4 == 0) gred[rr] = acc + gev;
    }
    __syncthreads();
    if (tid < 32) {
      float cc = sigm(gred[tid]) * tanhf(gred[32 + tid]);
      float h = sigm(gred[64 + tid]) * tanhf(cc);
      st2f(P + H0_OFF + 2 * (s * 32 + tid), h, tagf);   // fire-and-forget
    }

    // prefetch next ge (overlaps exchange)
    if (t + 1 < TT && rr < 96 && c4 == 0)
      gev = ge[(size_t)((t + 1) * 32 + b) * 1024 + rowA];

    // ---- exchange 1: per-lane poll-gather h0 (one 8B pair each) ----
    if (tid < 256) {
      const float* p = P + H0_OFF + 2 * tid;
      int it = 0;
      for (;;) {
        f32x2 hv = ld2(p);
        if (__float_as_int(hv[1]) == tag) { hbufh[tid] = (f16)hv[0]; break; }
        __builtin_amdgcn_s_sleep(1);
        if (++it > LIM) { dead = 1; break; }
      }
    }
    __syncthreads();
    if (dead) break;

    // ---- stage B: own L1 gate rows -> own h1[32] ----
    if (rr < 96) {
      float acc = 0.f;
#pragma unroll
      for (int i = 0; i < 8; ++i)
        acc = dot8h(wB[i], &hbufh[c4 * 64 + i * 8], acc);
      acc += __shfl_xor(acc, 1, 64);
      acc += __shfl_xor(acc, 2, 64);
      if (c4 == 0) gred[rr] = acc + b1v;
    }
    __syncthreads();
    if (tid < 32) {
      float cc = sigm(gred[tid]) * tanhf(gred[32 + tid]);
      h1h[tid] = (f16)(sigm(gred[64 + tid]) * tanhf(cc));
    }
    __syncthreads();

    // ---- stage B2: proj partial post (one self-tagged pair per thread) ----
    {
      float acc = 0.f;
#pragma unroll
      for (int i = 0; i < 4; ++i)
        acc = dot8h(wp[i], &h1h[i * 8], acc);
      st2f(P + PP_OFF + (tid * 8 + s) * 2, acc, tagf);
    }

    // ---- exchange 2: per-lane poll-gather own 64B run of 8 proj partials ----
    {
      const float* p = P + PP_OFF + 16 * tid;
      int it = 0;
      float v = 0.f;
      for (;;) {
        f32x4 o[4];
        ld4q(p, o);
        bool ok = (__float_as_int(o[0][1]) == tag) & (__float_as_int(o[0][3]) == tag)
                & (__float_as_int(o[1][1]) == tag) & (__float_as_int(o[1][3]) == tag)
                & (__float_as_int(o[2][1]) == tag) & (__float_as_int(o[2][3]) == tag)
                & (__float_as_int(o[3][1]) == tag) & (__float_as_int(o[3][3]) == tag);
        if (ok) {
          v = bpv + o[0][0] + o[0][2] + o[1][0] + o[1][2]
                  + o[2][0] + o[2][2] + o[3][0] + o[3][2];
          break;
        }
        __builtin_amdgcn_s_sleep(1);
        if (++it > LIM) { dead = 1; break; }
      }
      v = fmaxf(v, 0.f);
      projh[tid] = (f16)v;
      if (s == 0) pc[(size_t)(b * 256 + t) * 1024 + tid] = (f16)v;
    }
    __syncthreads();
    if (dead) break;

    // ---- stage D: scores (own 64 k-rows), local softmax, ctx partial post ----
    {
      int kk = rp;                       // 0..63
      int swz = (kk & 7) << 3;
      float acc = 0.f;
#pragma unroll
      for (int j0 = 0; j0 < 8; ++j0) {
        int d = j0 * 64 + c8 * 8;
        f16x8 v = *(const f16x8*)&ench[kk * 512 + (d ^ swz)];
        acc = dot8h(v, &projh[d], acc);
      }
      acc += __shfl_xor(acc, 1, 64);
      acc += __shfl_xor(acc, 2, 64);
      acc += __shfl_xor(acc, 4, 64);
      if (c8 == 0) sc_lds[kk] = acc;
    }
    __syncthreads();
    if (tid < 64) {
      float v = sc_lds[tid];
      float m = v;
      m = fmaxf(m, __shfl_xor(m, 32, 64));
      m = fmaxf(m, __shfl_xor(m, 16, 64));
      m = fmaxf(m, __shfl_xor(m, 8, 64));
      m = fmaxf(m, __shfl_xor(m, 4, 64));
      m = fmaxf(m, __shfl_xor(m, 2, 64));
      m = fmaxf(m, __shfl_xor(m, 1, 64));
      float e = __expf(v - m);
      el[tid] = e;
      float S = e;
      S += __shfl_xor(S, 32, 64);
      S += __shfl_xor(S, 16, 64);
      S += __shfl_xor(S, 8, 64);
      S += __shfl_xor(S, 4, 64);
      S += __shfl_xor(S, 2, 64);
      S += __shfl_xor(S, 1, 64);
      if (tid == 0) {
        f32x4 q; q[0] = m; q[1] = S; q[2] = tagf; q[3] = tagf;
        st4f(P + MS_OFF + 4 * s, q);
      }
    }
    __syncthreads();
    {
      float c = 0.f;
#pragma unroll 8
      for (int kk = 0; kk < 64; ++kk)
        c += el[kk] * (float)ench[kk * 512 + (tid ^ ((kk & 7) << 3))];
      st2f(P + CP_OFF + (tid * 8 + s) * 2, c, tagf);
    }

    // ---- exchange 3: per-lane poll-gather 8 ctx partials + (m,S,tag) quad ----
    {
      const float* p = P + CP_OFF + 16 * tid;
      const float* msp = P + MS_OFF + 4 * (tid & 7);
      int it = 0;
      float w = 0.f, vsum = 0.f, Sv = 0.f, mv = 0.f;
      f32x4 oo0, oo1, oo2, oo3;
      for (;;) {
        f32x4 o[4], ms;
        ld4q_ms(p, msp, o, &ms);
        bool ok = (__float_as_int(o[0][1]) == tag) & (__float_as_int(o[0][3]) == tag)
                & (__float_as_int(o[1][1]) == tag) & (__float_as_int(o[1][3]) == tag)
                & (__float_as_int(o[2][1]) == tag) & (__float_as_int(o[2][3]) == tag)
                & (__float_as_int(o[3][1]) == tag) & (__float_as_int(o[3][3]) == tag)
                & (__float_as_int(ms[2]) == tag);
        if (ok) {
          mv = ms[0]; Sv = ms[1];
          oo0 = o[0]; oo1 = o[1]; oo2 = o[2]; oo3 = o[3];
          break;
        }
        __builtin_amdgcn_s_sleep(1);
        if (++it > LIM) { dead = 1; break; }
      }
      // all lanes of the wave have reconverged here with their own data
      float mg = mv;
      mg = fmaxf(mg, __shfl_xor(mg, 1, 8));
      mg = fmaxf(mg, __shfl_xor(mg, 2, 8));
      mg = fmaxf(mg, __shfl_xor(mg, 4, 8));
      w = __expf(mv - mg);
      float Sg = w * Sv;
      Sg += __shfl_xor(Sg, 1, 8);
      Sg += __shfl_xor(Sg, 2, 8);
      Sg += __shfl_xor(Sg, 4, 8);
      float inv = 1.f / Sg;
      vsum = __shfl(w, 0, 8) * oo0[0] + __shfl(w, 1, 8) * oo0[2]
           + __shfl(w, 2, 8) * oo1[0] + __shfl(w, 3, 8) * oo1[2]
           + __shfl(w, 4, 8) * oo2[0] + __shfl(w, 5, 8) * oo2[2]
           + __shfl(w, 6, 8) * oo3[0] + __shfl(w, 7, 8) * oo3[2];
      vsum *= inv;
      ctxh[tid] = (f16)vsum;
      if (s == 0) pc[(size_t)(b * 256 + t) * 1024 + 512 + tid] = (f16)vsum;
    }
    __syncthreads();
    if (dead) break;
  }
}

// ---- K3: OUT[8192,10000] = PC[8192,1024] @ Wout16^T, fp16 MFMA ----
__global__ __launch_bounds__(256) void k_gemm(
    const f16* __restrict__ A, const f16* __restrict__ Bm, float* __restrict__ C)
{
  __shared__ f16 Ah[128 * 40];
  __shared__ f16 Bh[128 * 40];
  int tid = threadIdx.x;
  int tn = blockIdx.x;
  int tm = blockIdx.y;
  int lane = tid & 63, wave = tid >> 6;
  int wm = wave >> 1, wn = wave & 1;
  f32x4 acc[4][4];
#pragma unroll
  for (int i = 0; i < 4; ++i)
#pragma unroll
    for (int q = 0; q < 4; ++q) acc[i][q] = (f32x4){0.f, 0.f, 0.f, 0.f};

  for (int k0 = 0; k0 < 1024; k0 += 32) {
#pragma unroll
    for (int rd = 0; rd < 2; ++rd) {
      int chunk = tid + rd * 256;
      int row = chunk >> 2, cc = (chunk & 3) * 8;
      *(f16x8*)&Ah[row * 40 + cc] = *(const f16x8*)&A[((size_t)(tm * 128 + row)) * 1024 + k0 + cc];
      *(f16x8*)&Bh[row * 40 + cc] = *(const f16x8*)&Bm[((size_t)(tn * 128 + row)) * 1024 + k0 + cc];
    }
    __syncthreads();
    f16x8 af[4], bf[4];
#pragma unroll
    for (int q = 0; q < 4; ++q) {
      af[q] = *(const f16x8*)&Ah[(wm * 64 + q * 16 + (lane & 15)) * 40 + (lane >> 4) * 8];
      bf[q] = *(const f16x8*)&Bh[(wn * 64 + q * 16 + (lane & 15)) * 40 + (lane >> 4) * 8];
    }
#pragma unroll
    for (int i = 0; i < 4; ++i)
#pragma unroll
      for (int q = 0; q < 4; ++q)
        acc[i][q] = __builtin_amdgcn_mfma_f32_16x16x32_f16(af[i], bf[q], acc[i][q], 0, 0, 0);
    __syncthreads();
  }

  int rbase = (lane >> 4) * 4;
  int nloc = lane & 15;
#pragma unroll
  for (int i = 0; i < 4; ++i)
#pragma unroll
    for (int q = 0; q < 4; ++q)
#pragma unroll
      for (int rr = 0; rr < 4; ++rr) {
        int m = tm * 128 + wm * 64 + i * 16 + rbase + rr;
        int n = tn * 128 + wn * 64 + q * 16 + nloc;
        if (n < 10000) C[(size_t)m * 10000 + n] = acc[i][q][rr];
      }
}

extern "C" void kernel_launch(void* const* d_in, const int* in_sizes, int n_in,
                              void* d_out, int out_size, void* d_ws, size_t ws_size,
                              hipStream_t stream)
{
  const float* enc   = (const float*)d_in[0];
  const int*   dec   = (const int*)d_in[1];
  const float* emb   = (const float*)d_in[2];
  const float* Wih0  = (const float*)d_in[3];
  const float* b0    = (const float*)d_in[4];
  const float* Wih1  = (const float*)d_in[5];
  const float* b1    = (const float*)d_in[6];
  const float* Wproj = (const float*)d_in[7];
  const float* bproj = (const float*)d_in[8];
  const float* Wout  = (const float*)d_in[9];
  float* out = (float*)d_out;
  char* ws = (char*)d_ws;

  // zero the exchange region (tags must start at 0)
  hipMemsetAsync(ws + XC_OFF, 0, XC_BYTES, stream);
  k_embed_gates<<<1024, 256, 0, stream>>>(dec, emb, Wih0, b0, (float*)(ws + GE_OFF));
  k_wout_f16<<<(NPAD * 1024) / 4096, 256, 0, stream>>>(Wout, (f16*)(ws + WO_OFF));
  k_seq<<<256, 512, 0, stream>>>(enc, Wih0, Wih1, b1, Wproj, bproj,
                                 (float*)(ws + GE_OFF), (float*)(ws + XC_OFF),
                                 (f16*)(ws + PC_OFF));
  dim3 g3(79, 64);
  k_gemm<<<g3, 256, 0, stream>>>((const f16*)(ws + PC_OFF), (const f16*)(ws + WO_OFF), out);
}

// Round 11
// 2902.326 us; speedup vs baseline: 3.2023x; 2.5897x over previous
//
#include <hip/hip_runtime.h>
#include <hip/hip_fp16.h>

#define TT 256
#define NSL 8           // slices (blocks) per batch element
#define KR 64           // enc k-rows per slice
#define NPAD 10112
#define LIM (1 << 17)

typedef _Float16 f16;
typedef _Float16 f16x2h __attribute__((ext_vector_type(2)));
typedef _Float16 f16x8 __attribute__((ext_vector_type(8)));
typedef float f32x2 __attribute__((ext_vector_type(2)));
typedef float f32x4 __attribute__((ext_vector_type(4)));

// ---- per-b exchange layout (floats, per parity region). All entries are
// (value, tag) 8B pairs. WRITER-CONTIGUOUS: slice s owns contiguous regions
// so wave stores fill whole lines (no cross-CU false sharing).
#define H0_OFF 0        // 8 x 32 pairs = 512 floats
#define PP_OFF 512      // 8 x 512 pairs = 8192 (slice s at PP_OFF + s*1024)
#define MS_OFF 8704     // 8 x (m,S,tag,tag) = 32
#define CP_OFF 8736     // 8 x 512 pairs = 8192
#define PAR_STRIDE 16960
#define XC_STRIDE 34048ull

// ---- ws layout (bytes) ----
#define GE_OFF 4096ull
#define GE_BYTES (8192ull*1024ull*4ull)
#define XC_OFF (GE_OFF + GE_BYTES)
#define XC_BYTES (32ull*XC_STRIDE*4ull)
#define PC_OFF (XC_OFF + XC_BYTES)
#define PC_BYTES (8192ull*1024ull*2ull)
#define WO_OFF (PC_OFF + PC_BYTES)

__device__ __forceinline__ float sigm(float x) { return 1.f / (1.f + __expf(-x)); }

// ---- fire-and-forget MALL stores (self-tagged payloads, no acks) ----
__device__ __forceinline__ void st2f(float* p, float v, float tagf) {
  f32x2 x; x[0] = v; x[1] = tagf;
  asm volatile("global_store_dwordx2 %0, %1, off sc0 sc1" :: "v"(p), "v"(x) : "memory");
}
__device__ __forceinline__ void st4f(float* p, f32x4 v) {
  asm volatile("global_store_dwordx4 %0, %1, off sc0 sc1" :: "v"(p), "v"(v) : "memory");
}
// ---- gathers (with waitcnt) ----
__device__ __forceinline__ f32x2 ld2(const float* p) {
  f32x2 r;
  asm volatile("global_load_dwordx2 %0, %1, off sc0 sc1\n\ts_waitcnt vmcnt(0)"
               : "=v"(r) : "v"(p) : "memory");
  return r;
}
// 8 pipelined dwordx2 at 1024-float stride, one waitcnt (VGPR addresses)
__device__ __forceinline__ void ld8p(const float* base, f32x2* o) {
  asm volatile(
    "global_load_dwordx2 %0, %8, off sc0 sc1\n\t"
    "global_load_dwordx2 %1, %9, off sc0 sc1\n\t"
    "global_load_dwordx2 %2, %10, off sc0 sc1\n\t"
    "global_load_dwordx2 %3, %11, off sc0 sc1\n\t"
    "global_load_dwordx2 %4, %12, off sc0 sc1\n\t"
    "global_load_dwordx2 %5, %13, off sc0 sc1\n\t"
    "global_load_dwordx2 %6, %14, off sc0 sc1\n\t"
    "global_load_dwordx2 %7, %15, off sc0 sc1\n\t"
    "s_waitcnt vmcnt(0)"
    : "=&v"(o[0]), "=&v"(o[1]), "=&v"(o[2]), "=&v"(o[3]),
      "=&v"(o[4]), "=&v"(o[5]), "=&v"(o[6]), "=&v"(o[7])
    : "v"(base), "v"(base + 1024), "v"(base + 2048), "v"(base + 3072),
      "v"(base + 4096), "v"(base + 5120), "v"(base + 6144), "v"(base + 7168)
    : "memory");
}
// 8 pairs + 1 MS quad, one waitcnt
__device__ __forceinline__ void ld8p_ms(const float* base, const float* msp,
                                        f32x2* o, f32x4* ms) {
  asm volatile(
    "global_load_dwordx2 %0, %9, off sc0 sc1\n\t"
    "global_load_dwordx2 %1, %10, off sc0 sc1\n\t"
    "global_load_dwordx2 %2, %11, off sc0 sc1\n\t"
    "global_load_dwordx2 %3, %12, off sc0 sc1\n\t"
    "global_load_dwordx2 %4, %13, off sc0 sc1\n\t"
    "global_load_dwordx2 %5, %14, off sc0 sc1\n\t"
    "global_load_dwordx2 %6, %15, off sc0 sc1\n\t"
    "global_load_dwordx2 %7, %16, off sc0 sc1\n\t"
    "global_load_dwordx4 %8, %17, off sc0 sc1\n\t"
    "s_waitcnt vmcnt(0)"
    : "=&v"(o[0]), "=&v"(o[1]), "=&v"(o[2]), "=&v"(o[3]),
      "=&v"(o[4]), "=&v"(o[5]), "=&v"(o[6]), "=&v"(o[7]), "=&v"(*ms)
    : "v"(base), "v"(base + 1024), "v"(base + 2048), "v"(base + 3072),
      "v"(base + 4096), "v"(base + 5120), "v"(base + 6144), "v"(base + 7168),
      "v"(msp)
    : "memory");
}

// ---- f16 dot: 8 MACs via 4x v_dot2_f32_f16 ----
#if defined(__has_builtin)
#if __has_builtin(__builtin_amdgcn_fdot2)
#define HAS_FDOT2 1
#endif
#endif
__device__ __forceinline__ float dot8h(f16x8 w, const f16* x, float acc) {
#ifdef HAS_FDOT2
  const f16x2h* xp = (const f16x2h*)x;
  f16x2h w0; w0[0] = w[0]; w0[1] = w[1];
  f16x2h w1; w1[0] = w[2]; w1[1] = w[3];
  f16x2h w2; w2[0] = w[4]; w2[1] = w[5];
  f16x2h w3; w3[0] = w[6]; w3[1] = w[7];
  acc = __builtin_amdgcn_fdot2(w0, xp[0], acc, false);
  acc = __builtin_amdgcn_fdot2(w1, xp[1], acc, false);
  acc = __builtin_amdgcn_fdot2(w2, xp[2], acc, false);
  acc = __builtin_amdgcn_fdot2(w3, xp[3], acc, false);
#else
#pragma unroll
  for (int i = 0; i < 8; ++i) acc += (float)w[i] * (float)x[i];
#endif
  return acc;
}

// ---- K1: tokens -> embedding -> g_e = e @ W_e^T + b0 ----
__global__ __launch_bounds__(256) void k_embed_gates(
    const int* __restrict__ dec, const float* __restrict__ emb,
    const float* __restrict__ Wih0, const float* __restrict__ b0,
    float* __restrict__ ge)
{
  __shared__ float e_lds[8][64];
  int tid = threadIdx.x;
  int tb0 = blockIdx.x * 8;
  for (int j = tid; j < 8 * 64; j += 256) {
    int q = j >> 6, d = j & 63;
    int tb = tb0 + q;
    int t = tb >> 5, b = tb & 31;
    int tok;
    if (t == 0) tok = 1;
    else { tok = dec[b * 256 + (t - 1)]; if (tok == 2) tok = 0; }
    e_lds[q][d] = emb[(size_t)tok * 64 + d];
  }
  __syncthreads();
  for (int rr = 0; rr < 4; ++rr) {
    int row = tid + rr * 256;
    float bv = b0[row];
    float acc[8];
#pragma unroll
    for (int q = 0; q < 8; ++q) acc[q] = bv;
    const float* wr = Wih0 + (size_t)row * 576;
#pragma unroll 4
    for (int d4 = 0; d4 < 16; ++d4) {
      float4 w = *(const float4*)&wr[d4 * 4];
#pragma unroll
      for (int q = 0; q < 8; ++q) {
        acc[q] += w.x * e_lds[q][d4 * 4 + 0];
        acc[q] += w.y * e_lds[q][d4 * 4 + 1];
        acc[q] += w.z * e_lds[q][d4 * 4 + 2];
        acc[q] += w.w * e_lds[q][d4 * 4 + 3];
      }
    }
#pragma unroll
    for (int q = 0; q < 8; ++q) ge[(size_t)(tb0 + q) * 1024 + row] = acc[q];
  }
}

// ---- K1b: W_out fp32 -> fp16, padded ----
__global__ __launch_bounds__(256) void k_wout_f16(const float* __restrict__ W, f16* __restrict__ wo)
{
  size_t base = (size_t)blockIdx.x * 4096 + (size_t)threadIdx.x * 16;
  for (int i = 0; i < 16; ++i) {
    size_t idx = base + i;
    size_t n = idx >> 10;
    float v = (n < 10000) ? W[idx] : 0.f;
    wo[idx] = (f16)v;
  }
}

// ---- K2: 8 slices x 512 threads per b; tag-in-data, writer-contiguous ----
__global__ __launch_bounds__(512, 2) void k_seq(
    const float* __restrict__ enc, const float* __restrict__ Wih0,
    const float* __restrict__ Wih1, const float* __restrict__ b1,
    const float* __restrict__ Wproj, const float* __restrict__ bproj,
    const float* __restrict__ ge, float* __restrict__ xc,
    f16* __restrict__ pc)
{
  __shared__ f16 ench[KR * 512];       // 64KB
  __shared__ f16 ctxh[512];
  __shared__ f16 hbufh[256];
  __shared__ f16 projh[512];
  __shared__ f16 h1h[32];
  __shared__ float gred[96];
  __shared__ float sc_lds[64];
  __shared__ float el[64];
  __shared__ int dead;

  int tid = threadIdx.x;
  int j = blockIdx.x;
  int b = j & 31;                 // slices of b share blockIdx%8 residue
  int s = j >> 5;
  float* xcb = xc + (size_t)b * XC_STRIDE;

  int rr = tid >> 2, c4 = tid & 3;
  int rp = tid >> 3, c8 = tid & 7;

  // ---- fp16 register-stationary weights ----
  f16x8 wA[16];   // Wih0 ctx part: own gate row, 128 cols
  f16x8 wB[8];    // Wih1: own gate row, 64 cols
  f16x8 wp[4];    // Wproj: own row, 32 cols
  int rowA = 0; float b1v = 0.f;
  if (rr < 96) {
    int g = rr >> 5, d = rr & 31;
    rowA = (g == 0 ? 0 : g == 1 ? 512 : 768) + s * 32 + d;
    const float* wra = Wih0 + (size_t)rowA * 576 + 64 + c4 * 128;
#pragma unroll
    for (int i = 0; i < 16; ++i) {
      float4 x0 = ((const float4*)wra)[2 * i];
      float4 x1 = ((const float4*)wra)[2 * i + 1];
      f16x8 w;
      w[0]=(f16)x0.x; w[1]=(f16)x0.y; w[2]=(f16)x0.z; w[3]=(f16)x0.w;
      w[4]=(f16)x1.x; w[5]=(f16)x1.y; w[6]=(f16)x1.z; w[7]=(f16)x1.w;
      wA[i] = w;
    }
    const float* wrb = Wih1 + (size_t)rowA * 256 + c4 * 64;
#pragma unroll
    for (int i = 0; i < 8; ++i) {
      float4 x0 = ((const float4*)wrb)[2 * i];
      float4 x1 = ((const float4*)wrb)[2 * i + 1];
      f16x8 w;
      w[0]=(f16)x0.x; w[1]=(f16)x0.y; w[2]=(f16)x0.z; w[3]=(f16)x0.w;
      w[4]=(f16)x1.x; w[5]=(f16)x1.y; w[6]=(f16)x1.z; w[7]=(f16)x1.w;
      wB[i] = w;
    }
    b1v = b1[rowA];
  }
  {
    const float* wpr = Wproj + (size_t)tid * 256 + s * 32;
#pragma unroll
    for (int i = 0; i < 4; ++i) {
      float4 x0 = ((const float4*)wpr)[2 * i];
      float4 x1 = ((const float4*)wpr)[2 * i + 1];
      f16x8 w;
      w[0]=(f16)x0.x; w[1]=(f16)x0.y; w[2]=(f16)x0.z; w[3]=(f16)x0.w;
      w[4]=(f16)x1.x; w[5]=(f16)x1.y; w[6]=(f16)x1.z; w[7]=(f16)x1.w;
      wp[i] = w;
    }
  }
  float bpv = bproj[tid];

  // stationary enc slice -> LDS fp16, xor swizzle on d by (kk&7)<<3
  for (int i = tid; i < KR * 512; i += 512) {
    int kk = i >> 9, d = i & 511;
    float v = enc[((size_t)b * 512 + s * KR + kk) * 512 + d];
    ench[kk * 512 + (d ^ ((kk & 7) << 3))] = (f16)v;
  }
  ctxh[tid] = (f16)0.f;
  if (tid == 0) dead = 0;
  __syncthreads();

  float gev = 0.f;
  if (rr < 96 && c4 == 0) gev = ge[(size_t)b * 1024 + rowA];   // t=0

  for (int t = 0; t < TT; ++t) {
    float* P = xcb + (t & 1) * PAR_STRIDE;
    int tag = t + 1;
    float tagf = __int_as_float(tag);

    // ---- stage A: own L0 gate rows = g_e + W_c @ ctx -> post own h0[32] ----
    if (rr < 96) {
      float acc = 0.f;
#pragma unroll
      for (int i = 0; i < 16; ++i)
        acc = dot8h(wA[i], &ctxh[c4 * 128 + i * 8], acc);
      acc += __shfl_xor(acc, 1, 64);
      acc += __shfl_xor(acc, 2, 64);
      if (c4 == 0) gred[rr] = acc + gev;
    }
    __syncthreads();
    if (tid < 32) {
      float cc = sigm(gred[tid]) * tanhf(gred[32 + tid]);
      float h = sigm(gred[64 + tid]) * tanhf(cc);
      st2f(P + H0_OFF + 2 * (s * 32 + tid), h, tagf);   // own contiguous 256B
    }

    // prefetch next ge (overlaps exchange)
    if (t + 1 < TT && rr < 96 && c4 == 0)
      gev = ge[(size_t)((t + 1) * 32 + b) * 1024 + rowA];

    // ---- exchange 1: per-lane poll-gather h0 (one 8B pair each) ----
    if (tid < 256) {
      const float* p = P + H0_OFF + 2 * tid;
      int it = 0;
      for (;;) {
        f32x2 hv = ld2(p);
        if (__float_as_int(hv[1]) == tag) { hbufh[tid] = (f16)hv[0]; break; }
        __builtin_amdgcn_s_sleep(1);
        if (++it > LIM) { dead = 1; break; }
      }
    }
    __syncthreads();
    if (dead) break;

    // ---- stage B: own L1 gate rows -> own h1[32] ----
    if (rr < 96) {
      float acc = 0.f;
#pragma unroll
      for (int i = 0; i < 8; ++i)
        acc = dot8h(wB[i], &hbufh[c4 * 64 + i * 8], acc);
      acc += __shfl_xor(acc, 1, 64);
      acc += __shfl_xor(acc, 2, 64);
      if (c4 == 0) gred[rr] = acc + b1v;
    }
    __syncthreads();
    if (tid < 32) {
      float cc = sigm(gred[tid]) * tanhf(gred[32 + tid]);
      h1h[tid] = (f16)(sigm(gred[64 + tid]) * tanhf(cc));
    }
    __syncthreads();

    // ---- stage B2: proj partial post into slice-owned region ----
    {
      float acc = 0.f;
#pragma unroll
      for (int i = 0; i < 4; ++i)
        acc = dot8h(wp[i], &h1h[i * 8], acc);
      st2f(P + PP_OFF + s * 1024 + 2 * tid, acc, tagf);
    }

    // ---- exchange 2: per-lane poll-gather 8 strided proj pairs ----
    {
      const float* p = P + PP_OFF + 2 * tid;
      int it = 0;
      float v = 0.f;
      for (;;) {
        f32x2 o[8];
        ld8p(p, o);
        bool ok = true;
#pragma unroll
        for (int q = 0; q < 8; ++q) ok &= (__float_as_int(o[q][1]) == tag);
        if (ok) {
          v = bpv;
#pragma unroll
          for (int q = 0; q < 8; ++q) v += o[q][0];
          break;
        }
        __builtin_amdgcn_s_sleep(1);
        if (++it > LIM) { dead = 1; break; }
      }
      v = fmaxf(v, 0.f);
      projh[tid] = (f16)v;
      if (s == 0) pc[(size_t)(b * 256 + t) * 1024 + tid] = (f16)v;
    }
    __syncthreads();
    if (dead) break;

    // ---- stage D: scores (own 64 k-rows), local softmax, ctx partial post ----
    {
      int kk = rp;                       // 0..63
      int swz = (kk & 7) << 3;
      float acc = 0.f;
#pragma unroll
      for (int j0 = 0; j0 < 8; ++j0) {
        int d = j0 * 64 + c8 * 8;
        f16x8 v = *(const f16x8*)&ench[kk * 512 + (d ^ swz)];
        acc = dot8h(v, &projh[d], acc);
      }
      acc += __shfl_xor(acc, 1, 64);
      acc += __shfl_xor(acc, 2, 64);
      acc += __shfl_xor(acc, 4, 64);
      if (c8 == 0) sc_lds[kk] = acc;
    }
    __syncthreads();
    if (tid < 64) {
      float v = sc_lds[tid];
      float m = v;
      m = fmaxf(m, __shfl_xor(m, 32, 64));
      m = fmaxf(m, __shfl_xor(m, 16, 64));
      m = fmaxf(m, __shfl_xor(m, 8, 64));
      m = fmaxf(m, __shfl_xor(m, 4, 64));
      m = fmaxf(m, __shfl_xor(m, 2, 64));
      m = fmaxf(m, __shfl_xor(m, 1, 64));
      float e = __expf(v - m);
      el[tid] = e;
      float S = e;
      S += __shfl_xor(S, 32, 64);
      S += __shfl_xor(S, 16, 64);
      S += __shfl_xor(S, 8, 64);
      S += __shfl_xor(S, 4, 64);
      S += __shfl_xor(S, 2, 64);
      S += __shfl_xor(S, 1, 64);
      if (tid == 0) {
        f32x4 q; q[0] = m; q[1] = S; q[2] = tagf; q[3] = tagf;
        st4f(P + MS_OFF + 4 * s, q);
      }
    }
    __syncthreads();
    {
      float c = 0.f;
#pragma unroll 8
      for (int kk = 0; kk < 64; ++kk)
        c += el[kk] * (float)ench[kk * 512 + (tid ^ ((kk & 7) << 3))];
      st2f(P + CP_OFF + s * 1024 + 2 * tid, c, tagf);
    }

    // ---- exchange 3: per-lane poll-gather 8 strided ctx pairs + MS quad ----
    {
      const float* p = P + CP_OFF + 2 * tid;
      const float* msp = P + MS_OFF + 4 * (tid & 7);
      int it = 0;
      float mv = 0.f, Sv = 0.f;
      f32x2 oo[8];
      for (;;) {
        f32x2 o[8]; f32x4 ms;
        ld8p_ms(p, msp, o, &ms);
        bool ok = (__float_as_int(ms[2]) == tag);
#pragma unroll
        for (int q = 0; q < 8; ++q) ok &= (__float_as_int(o[q][1]) == tag);
        if (ok) {
          mv = ms[0]; Sv = ms[1];
#pragma unroll
          for (int q = 0; q < 8; ++q) oo[q] = o[q];
          break;
        }
        __builtin_amdgcn_s_sleep(1);
        if (++it > LIM) { dead = 1; break; }
      }
      float mg = mv;
      mg = fmaxf(mg, __shfl_xor(mg, 1, 8));
      mg = fmaxf(mg, __shfl_xor(mg, 2, 8));
      mg = fmaxf(mg, __shfl_xor(mg, 4, 8));
      float w = __expf(mv - mg);
      float Sg = w * Sv;
      Sg += __shfl_xor(Sg, 1, 8);
      Sg += __shfl_xor(Sg, 2, 8);
      Sg += __shfl_xor(Sg, 4, 8);
      float inv = 1.f / Sg;
      float vsum = 0.f;
#pragma unroll
      for (int q = 0; q < 8; ++q) vsum += __shfl(w, q, 8) * oo[q][0];
      vsum *= inv;
      ctxh[tid] = (f16)vsum;
      if (s == 0) pc[(size_t)(b * 256 + t) * 1024 + 512 + tid] = (f16)vsum;
    }
    __syncthreads();
    if (dead) break;
  }
}

// ---- K3: OUT[8192,10000] = PC[8192,1024] @ Wout16^T, fp16 MFMA ----
__global__ __launch_bounds__(256) void k_gemm(
    const f16* __restrict__ A, const f16* __restrict__ Bm, float* __restrict__ C)
{
  __shared__ f16 Ah[128 * 40];
  __shared__ f16 Bh[128 * 40];
  int tid = threadIdx.x;
  int tn = blockIdx.x;
  int tm = blockIdx.y;
  int lane = tid & 63, wave = tid >> 6;
  int wm = wave >> 1, wn = wave & 1;
  f32x4 acc[4][4];
#pragma unroll
  for (int i = 0; i < 4; ++i)
#pragma unroll
    for (int q = 0; q < 4; ++q) acc[i][q] = (f32x4){0.f, 0.f, 0.f, 0.f};

  for (int k0 = 0; k0 < 1024; k0 += 32) {
#pragma unroll
    for (int rd = 0; rd < 2; ++rd) {
      int chunk = tid + rd * 256;
      int row = chunk >> 2, cc = (chunk & 3) * 8;
      *(f16x8*)&Ah[row * 40 + cc] = *(const f16x8*)&A[((size_t)(tm * 128 + row)) * 1024 + k0 + cc];
      *(f16x8*)&Bh[row * 40 + cc] = *(const f16x8*)&Bm[((size_t)(tn * 128 + row)) * 1024 + k0 + cc];
    }
    __syncthreads();
    f16x8 af[4], bf[4];
#pragma unroll
    for (int q = 0; q < 4; ++q) {
      af[q] = *(const f16x8*)&Ah[(wm * 64 + q * 16 + (lane & 15)) * 40 + (lane >> 4) * 8];
      bf[q] = *(const f16x8*)&Bh[(wn * 64 + q * 16 + (lane & 15)) * 40 + (lane >> 4) * 8];
    }
#pragma unroll
    for (int i = 0; i < 4; ++i)
#pragma unroll
      for (int q = 0; q < 4; ++q)
        acc[i][q] = __builtin_amdgcn_mfma_f32_16x16x32_f16(af[i], bf[q], acc[i][q], 0, 0, 0);
    __syncthreads();
  }

  int rbase = (lane >> 4) * 4;
  int nloc = lane & 15;
#pragma unroll
  for (int i = 0; i < 4; ++i)
#pragma unroll
    for (int q = 0; q < 4; ++q)
#pragma unroll
      for (int rr = 0; rr < 4; ++rr) {
        int m = tm * 128 + wm * 64 + i * 16 + rbase + rr;
        int n = tn * 128 + wn * 64 + q * 16 + nloc;
        if (n < 10000) C[(size_t)m * 10000 + n] = acc[i][q][rr];
      }
}

extern "C" void kernel_launch(void* const* d_in, const int* in_sizes, int n_in,
                              void* d_out, int out_size, void* d_ws, size_t ws_size,
                              hipStream_t stream)
{
  const float* enc   = (const float*)d_in[0];
  const int*   dec   = (const int*)d_in[1];
  const float* emb   = (const float*)d_in[2];
  const float* Wih0  = (const float*)d_in[3];
  const float* b0    = (const float*)d_in[4];
  const float* Wih1  = (const float*)d_in[5];
  const float* b1    = (const float*)d_in[6];
  const float* Wproj = (const float*)d_in[7];
  const float* bproj = (const float*)d_in[8];
  const float* Wout  = (const float*)d_in[9];
  float* out = (float*)d_out;
  char* ws = (char*)d_ws;

  // zero the exchange region (tags must start at 0)
  hipMemsetAsync(ws + XC_OFF, 0, XC_BYTES, stream);
  k_embed_gates<<<1024, 256, 0, stream>>>(dec, emb, Wih0, b0, (float*)(ws + GE_OFF));
  k_wout_f16<<<(NPAD * 1024) / 4096, 256, 0, stream>>>(Wout, (f16*)(ws + WO_OFF));
  k_seq<<<256, 512, 0, stream>>>(enc, Wih0, Wih1, b1, Wproj, bproj,
                                 (float*)(ws + GE_OFF), (float*)(ws + XC_OFF),
                                 (f16*)(ws + PC_OFF));
  dim3 g3(79, 64);
  k_gemm<<<g3, 256, 0, stream>>>((const f16*)(ws + PC_OFF), (const f16*)(ws + WO_OFF), out);
}